// Round 1
// baseline (3533.834 us; speedup 1.0000x reference)
//
#include <hip/hip_runtime.h>
#include <hip/hip_bf16.h>
#include <cstdint>

#define HIDDEN 2048
#define NHEADS 16
#define DH 128
#define BATCH 2
#define SEQ 2048
#define MTOT (BATCH * SEQ) /* 4096 */

static constexpr float ATTN_SCALE = 0.08838834764831845f; // 128^-0.5

// ---------------------------------------------------------------------------
// GEMM (fp32): C = A[M,K] @ W[N,K]^T
// MODE 0: C[m*N + n]                          (used for the O projection)
// MODE 1: C[((b*NHEADS+h)*SEQ + s)*DH + d]    (per-head [B,H,S,D] for Q/K/V)
// 128x128 tile, BK=16, 256 threads, 8x8 per thread, k-major LDS.
// ---------------------------------------------------------------------------
template <int MODE>
__global__ __launch_bounds__(256) void gemm_nt_f32(const float* __restrict__ A,
                                                   const float* __restrict__ W,
                                                   float* __restrict__ C,
                                                   int K, int N) {
  __shared__ float As[16][132];
  __shared__ float Ws[16][132];
  const int tid = threadIdx.x;
  const int m0 = blockIdx.y * 128;
  const int n0 = blockIdx.x * 128;
  const int ty = tid >> 4;        // 0..15 -> output rows ty*8..ty*8+7
  const int tx = tid & 15;        // 0..15 -> output cols tx*8..tx*8+7
  const int lr = tid >> 2;        // 0..63  staging row
  const int lc = (tid & 3) << 2;  // 0,4,8,12 staging k-offset

  float acc[8][8];
#pragma unroll
  for (int i = 0; i < 8; ++i)
#pragma unroll
    for (int j = 0; j < 8; ++j) acc[i][j] = 0.f;

  for (int k0 = 0; k0 < K; k0 += 16) {
    // global loads into registers (before barrier so they overlap readers)
    float4 a0 = *(const float4*)&A[(size_t)(m0 + lr) * K + k0 + lc];
    float4 a1 = *(const float4*)&A[(size_t)(m0 + lr + 64) * K + k0 + lc];
    float4 w0 = *(const float4*)&W[(size_t)(n0 + lr) * K + k0 + lc];
    float4 w1 = *(const float4*)&W[(size_t)(n0 + lr + 64) * K + k0 + lc];
    __syncthreads();  // previous iteration finished reading LDS
    As[lc + 0][lr] = a0.x; As[lc + 1][lr] = a0.y;
    As[lc + 2][lr] = a0.z; As[lc + 3][lr] = a0.w;
    As[lc + 0][lr + 64] = a1.x; As[lc + 1][lr + 64] = a1.y;
    As[lc + 2][lr + 64] = a1.z; As[lc + 3][lr + 64] = a1.w;
    Ws[lc + 0][lr] = w0.x; Ws[lc + 1][lr] = w0.y;
    Ws[lc + 2][lr] = w0.z; Ws[lc + 3][lr] = w0.w;
    Ws[lc + 0][lr + 64] = w1.x; Ws[lc + 1][lr + 64] = w1.y;
    Ws[lc + 2][lr + 64] = w1.z; Ws[lc + 3][lr + 64] = w1.w;
    __syncthreads();

#pragma unroll
    for (int kk = 0; kk < 16; ++kk) {
      float a[8], w[8];
      *(float4*)&a[0] = *(const float4*)&As[kk][ty * 8];
      *(float4*)&a[4] = *(const float4*)&As[kk][ty * 8 + 4];
      *(float4*)&w[0] = *(const float4*)&Ws[kk][tx * 8];
      *(float4*)&w[4] = *(const float4*)&Ws[kk][tx * 8 + 4];
#pragma unroll
      for (int i = 0; i < 8; ++i)
#pragma unroll
        for (int j = 0; j < 8; ++j) acc[i][j] = fmaf(a[i], w[j], acc[i][j]);
    }
  }

#pragma unroll
  for (int i = 0; i < 8; ++i) {
    const int m = m0 + ty * 8 + i;
#pragma unroll
    for (int j = 0; j < 8; ++j) {
      const int n = n0 + tx * 8 + j;
      if (MODE == 0) {
        C[(size_t)m * N + n] = acc[i][j];
      } else {
        const int b = m >> 11;          // m / SEQ
        const int s = m & (SEQ - 1);
        const int h = n >> 7;           // n / DH
        const int d = n & (DH - 1);
        C[(((size_t)(b * NHEADS + h) * SEQ) + s) * DH + d] = acc[i][j];
      }
    }
  }
}

// ---------------------------------------------------------------------------
// Flash attention (fp32), per (b,h): Q,K,V are [SEQ][DH] slices of [B,H,S,D].
// Block: 256 threads = 32 q-rows x 8 lanes. BKV = 32 keys per tile.
// Each thread: 4 scores/tile (keys l8 + 8j), owns 16 output dims
// (d = d4*32 + l8*4 + i), online softmax with P shared via LDS.
// Output written to Aout in [B,S,H,D] layout (feeds the O-GEMM directly).
// ---------------------------------------------------------------------------
__global__ __launch_bounds__(256) void flash_f32(const float* __restrict__ Q,
                                                 const float* __restrict__ K,
                                                 const float* __restrict__ V,
                                                 float* __restrict__ Aout) {
  const int bh = blockIdx.y;  // b*NHEADS + h
  const int q0 = blockIdx.x * 32;
  const int tid = threadIdx.x;
  const int r = tid >> 3;   // 0..31 q-row within tile
  const int l8 = tid & 7;   // lane within row

  const float* Qh = Q + (size_t)bh * SEQ * DH;
  const float* Kh = K + (size_t)bh * SEQ * DH;
  const float* Vh = V + (size_t)bh * SEQ * DH;

  __shared__ float Qs[32][132];
  __shared__ float Ks[32][132];
  __shared__ float Vs[32][132];
  __shared__ float Ps[32][36];

  // stage Q tile (32 x 128)
  for (int i = tid; i < 32 * 32; i += 256) {
    const int rr = i >> 5;
    const int cc = (i & 31) << 2;
    *(float4*)&Qs[rr][cc] = *(const float4*)&Qh[(size_t)(q0 + rr) * DH + cc];
  }

  float acc[16];
#pragma unroll
  for (int i = 0; i < 16; ++i) acc[i] = 0.f;
  float m_run = -1e30f;
  float l_run = 0.f;

  for (int t = 0; t < SEQ; t += 32) {
    __syncthreads();  // previous tile fully consumed (also covers Q staging)
    for (int i = tid; i < 32 * 32; i += 256) {
      const int rr = i >> 5;
      const int cc = (i & 31) << 2;
      *(float4*)&Ks[rr][cc] = *(const float4*)&Kh[(size_t)(t + rr) * DH + cc];
      *(float4*)&Vs[rr][cc] = *(const float4*)&Vh[(size_t)(t + rr) * DH + cc];
    }
    __syncthreads();

    // scores for keys kj = l8 + 8*j
    float s[4] = {0.f, 0.f, 0.f, 0.f};
#pragma unroll 8
    for (int d4 = 0; d4 < 32; ++d4) {
      const float4 q4 = *(const float4*)&Qs[r][d4 * 4];
#pragma unroll
      for (int j = 0; j < 4; ++j) {
        const float4 k4 = *(const float4*)&Ks[l8 + 8 * j][d4 * 4];
        s[j] = fmaf(q4.x, k4.x, s[j]);
        s[j] = fmaf(q4.y, k4.y, s[j]);
        s[j] = fmaf(q4.z, k4.z, s[j]);
        s[j] = fmaf(q4.w, k4.w, s[j]);
      }
    }
#pragma unroll
    for (int j = 0; j < 4; ++j) s[j] *= ATTN_SCALE;

    // row max across 4 local + 8 lanes
    float mt = fmaxf(fmaxf(s[0], s[1]), fmaxf(s[2], s[3]));
#pragma unroll
    for (int o = 1; o < 8; o <<= 1) mt = fmaxf(mt, __shfl_xor(mt, o));
    const float m_new = fmaxf(m_run, mt);
    const float corr = __expf(m_run - m_new);

    float p[4], ls = 0.f;
#pragma unroll
    for (int j = 0; j < 4; ++j) {
      p[j] = __expf(s[j] - m_new);
      ls += p[j];
    }
#pragma unroll
    for (int o = 1; o < 8; o <<= 1) ls += __shfl_xor(ls, o);
    l_run = l_run * corr + ls;
    m_run = m_new;
#pragma unroll
    for (int i = 0; i < 16; ++i) acc[i] *= corr;

    // share P across the row's 8 lanes
#pragma unroll
    for (int j = 0; j < 4; ++j) Ps[r][l8 + 8 * j] = p[j];
    __syncthreads();

    // PV: thread owns d = d4*32 + l8*4 + i  (conflict-free Vs reads)
    for (int kk = 0; kk < 32; ++kk) {
      const float pk = Ps[r][kk];
#pragma unroll
      for (int d4 = 0; d4 < 4; ++d4) {
        const float4 v4 = *(const float4*)&Vs[kk][d4 * 32 + l8 * 4];
        acc[d4 * 4 + 0] = fmaf(pk, v4.x, acc[d4 * 4 + 0]);
        acc[d4 * 4 + 1] = fmaf(pk, v4.y, acc[d4 * 4 + 1]);
        acc[d4 * 4 + 2] = fmaf(pk, v4.z, acc[d4 * 4 + 2]);
        acc[d4 * 4 + 3] = fmaf(pk, v4.w, acc[d4 * 4 + 3]);
      }
    }
  }

  const float inv = 1.f / l_run;
  const int s_idx = q0 + r;
  const int b = bh >> 4;
  const int h = bh & 15;
  float* dst = Aout + (((size_t)(b * SEQ + s_idx) * NHEADS) + h) * DH;
#pragma unroll
  for (int d4 = 0; d4 < 4; ++d4) {
    float4 o;
    o.x = acc[d4 * 4 + 0] * inv;
    o.y = acc[d4 * 4 + 1] * inv;
    o.z = acc[d4 * 4 + 2] * inv;
    o.w = acc[d4 * 4 + 3] * inv;
    *(float4*)&dst[d4 * 32 + l8 * 4] = o;
  }
}

// ---------------------------------------------------------------------------
extern "C" void kernel_launch(void* const* d_in, const int* in_sizes, int n_in,
                              void* d_out, int out_size, void* d_ws,
                              size_t ws_size, hipStream_t stream) {
  const float* X  = (const float*)d_in[0];
  const float* Wq = (const float*)d_in[1];
  const float* Wk = (const float*)d_in[2];
  const float* Wv = (const float*)d_in[3];
  const float* Wo = (const float*)d_in[4];
  float* out = (float*)d_out;

  // workspace: Q,K,V in [B,H,S,D] + attn-out in [B,S,H,D], all fp32
  const size_t elems = (size_t)MTOT * HIDDEN;  // 8388608
  float* Qb = (float*)d_ws;
  float* Kb = Qb + elems;
  float* Vb = Kb + elems;
  float* Ab = Vb + elems;

  const dim3 ggrid(HIDDEN / 128, MTOT / 128);  // (16, 32)
  gemm_nt_f32<1><<<ggrid, 256, 0, stream>>>(X, Wq, Qb, HIDDEN, HIDDEN);
  gemm_nt_f32<1><<<ggrid, 256, 0, stream>>>(X, Wk, Kb, HIDDEN, HIDDEN);
  gemm_nt_f32<1><<<ggrid, 256, 0, stream>>>(X, Wv, Vb, HIDDEN, HIDDEN);

  const dim3 fgrid(SEQ / 32, BATCH * NHEADS);  // (64, 32)
  flash_f32<<<fgrid, 256, 0, stream>>>(Qb, Kb, Vb, Ab);

  gemm_nt_f32<0><<<ggrid, 256, 0, stream>>>(Ab, Wo, out, HIDDEN, HIDDEN);
}

// Round 2
// 507.878 us; speedup vs baseline: 6.9580x; 6.9580x over previous
//
#include <hip/hip_runtime.h>
#include <cstdint>

#define HIDDEN 2048
#define NHEADS 16
#define DH 128
#define BATCH 2
#define SEQ 2048
#define MTOT 4096
#define BH (BATCH * NHEADS)

typedef __attribute__((ext_vector_type(8))) short bf16x8;
typedef __attribute__((ext_vector_type(4))) float f32x4;

static constexpr float ATTN_SCALE = 0.08838834764831845f; // 128^-0.5

__device__ __forceinline__ unsigned short f2bf(float f) {
  union { float f; uint32_t u; } v; v.f = f;
  uint32_t r = v.u + 0x7FFFu + ((v.u >> 16) & 1u);
  return (unsigned short)(r >> 16);
}
__device__ __forceinline__ float bf2f(unsigned short h) {
  union { uint32_t u; float f; } v; v.u = ((uint32_t)h) << 16;
  return v.f;
}
__device__ __forceinline__ uint32_t pack2bf(float a, float b) {
  return (uint32_t)f2bf(a) | ((uint32_t)f2bf(b) << 16);
}
__device__ __forceinline__ f32x4 mfma16(bf16x8 a, bf16x8 b, f32x4 c) {
  return __builtin_amdgcn_mfma_f32_16x16x32_bf16(a, b, c, 0, 0, 0);
}

// ---------------------------------------------------------------------------
// casts
// ---------------------------------------------------------------------------
__global__ __launch_bounds__(256) void cast_bf16_kernel(const float* __restrict__ in,
                                                        unsigned short* __restrict__ out,
                                                        int n) {
  int i = (blockIdx.x * 256 + threadIdx.x) * 4;
  if (i < n) {
    float4 f = *(const float4*)&in[i];
    ushort4 o;
    o.x = f2bf(f.x); o.y = f2bf(f.y); o.z = f2bf(f.z); o.w = f2bf(f.w);
    *(ushort4*)&out[i] = o;
  }
}

__global__ __launch_bounds__(256) void cast_split_kernel(const float* __restrict__ in,
                                                         unsigned short* __restrict__ hi,
                                                         unsigned short* __restrict__ lo,
                                                         int n) {
  int i = (blockIdx.x * 256 + threadIdx.x) * 4;
  if (i < n) {
    float4 f = *(const float4*)&in[i];
    ushort4 h, l;
    h.x = f2bf(f.x); l.x = f2bf(f.x - bf2f(h.x));
    h.y = f2bf(f.y); l.y = f2bf(f.y - bf2f(h.y));
    h.z = f2bf(f.z); l.z = f2bf(f.z - bf2f(h.z));
    h.w = f2bf(f.w); l.w = f2bf(f.w - bf2f(h.w));
    *(ushort4*)&hi[i] = h;
    *(ushort4*)&lo[i] = l;
  }
}

// ---------------------------------------------------------------------------
// V transpose: [BH][SEQ][DH] -> [BH][DH][SEQ]  (bf16)
// ---------------------------------------------------------------------------
__global__ __launch_bounds__(256) void transpose_v(const unsigned short* __restrict__ Vb,
                                                   unsigned short* __restrict__ Vt) {
  __shared__ unsigned short T[32][36];
  const int bh = blockIdx.z;
  const int s0 = blockIdx.x * 32, d0 = blockIdx.y * 32;
  const int tid = threadIdx.x;
  {
    int r = tid >> 3, c = (tid & 7) * 4;
    *(ushort4*)&T[r][c] =
        *(const ushort4*)&Vb[((size_t)bh * SEQ + s0 + r) * DH + d0 + c];
  }
  __syncthreads();
  {
    int d = tid >> 3, s = (tid & 7) * 4;
    ushort4 o;
    o.x = T[s + 0][d]; o.y = T[s + 1][d]; o.z = T[s + 2][d]; o.w = T[s + 3][d];
    *(ushort4*)&Vt[((size_t)bh * DH + d0 + d) * SEQ + s0 + s] = o;
  }
}

// ---------------------------------------------------------------------------
// Plain bf16 MFMA GEMM: C = alpha * A[M,K] @ W[N,K]^T, bf16 in, bf16 out.
// MODE 0: flat [M][N]; MODE 1: per-head [B,H,S,D] (col -> h,d; row -> b,s)
// 128x128 tile, BK=32, 256 thr (4 waves 2x2, each 64x64 = 4x4 frags).
// ---------------------------------------------------------------------------
template <int MODE>
__global__ __launch_bounds__(256) void gemm_bf16(const unsigned short* __restrict__ A,
                                                 const unsigned short* __restrict__ W,
                                                 unsigned short* __restrict__ C,
                                                 float alpha) {
  __shared__ unsigned short As[128][40];
  __shared__ unsigned short Ws[128][40];
  const int tid = threadIdx.x;
  const int lane = tid & 63, wid = tid >> 6;
  const int wr = wid >> 1, wc = wid & 1;
  const int g = lane >> 4, lr = lane & 15;
  const int m0 = blockIdx.y * 128, n0 = blockIdx.x * 128;
  const int srow = tid >> 2, skc = (tid & 3) * 8;

  f32x4 acc[4][4];
#pragma unroll
  for (int i = 0; i < 4; ++i)
#pragma unroll
    for (int j = 0; j < 4; ++j) acc[i][j] = (f32x4){0.f, 0.f, 0.f, 0.f};

  for (int k0 = 0; k0 < HIDDEN; k0 += 32) {
    bf16x8 a0 = *(const bf16x8*)&A[(size_t)(m0 + srow) * HIDDEN + k0 + skc];
    bf16x8 a1 = *(const bf16x8*)&A[(size_t)(m0 + srow + 64) * HIDDEN + k0 + skc];
    bf16x8 w0 = *(const bf16x8*)&W[(size_t)(n0 + srow) * HIDDEN + k0 + skc];
    bf16x8 w1 = *(const bf16x8*)&W[(size_t)(n0 + srow + 64) * HIDDEN + k0 + skc];
    __syncthreads();
    *(bf16x8*)&As[srow][skc] = a0;
    *(bf16x8*)&As[srow + 64][skc] = a1;
    *(bf16x8*)&Ws[srow][skc] = w0;
    *(bf16x8*)&Ws[srow + 64][skc] = w1;
    __syncthreads();

    bf16x8 af[4], wf[4];
#pragma unroll
    for (int mi = 0; mi < 4; ++mi)
      af[mi] = *(const bf16x8*)&As[wr * 64 + mi * 16 + lr][g * 8];
#pragma unroll
    for (int ni = 0; ni < 4; ++ni)
      wf[ni] = *(const bf16x8*)&Ws[wc * 64 + ni * 16 + lr][g * 8];
#pragma unroll
    for (int mi = 0; mi < 4; ++mi)
#pragma unroll
      for (int ni = 0; ni < 4; ++ni)
        acc[mi][ni] = mfma16(af[mi], wf[ni], acc[mi][ni]);
  }

#pragma unroll
  for (int mi = 0; mi < 4; ++mi)
#pragma unroll
    for (int ni = 0; ni < 4; ++ni)
#pragma unroll
      for (int r = 0; r < 4; ++r) {
        const int row = m0 + wr * 64 + mi * 16 + g * 4 + r;
        const int col = n0 + wc * 64 + ni * 16 + lr;
        const unsigned short v = f2bf(acc[mi][ni][r] * alpha);
        if (MODE == 0) {
          C[(size_t)row * HIDDEN + col] = v;
        } else {
          const int b = row >> 11, s = row & (SEQ - 1);
          const int h = col >> 7, d = col & (DH - 1);
          C[(((size_t)(b * NHEADS + h) * SEQ) + s) * DH + d] = v;
        }
      }
}

// ---------------------------------------------------------------------------
// Split-bf16x3 GEMM: C(fp32) = (Ah+Al)[M,K] @ (Wh+Wl)[N,K]^T
// (drops Al*Wl term; ~2^-17 relative accuracy)
// ---------------------------------------------------------------------------
__global__ __launch_bounds__(256) void gemm_split3(const unsigned short* __restrict__ Ah,
                                                   const unsigned short* __restrict__ Al,
                                                   const unsigned short* __restrict__ Wh,
                                                   const unsigned short* __restrict__ Wl,
                                                   float* __restrict__ C) {
  __shared__ unsigned short Ahs[128][40];
  __shared__ unsigned short Als[128][40];
  __shared__ unsigned short Whs[128][40];
  __shared__ unsigned short Wls[128][40];
  const int tid = threadIdx.x;
  const int lane = tid & 63, wid = tid >> 6;
  const int wr = wid >> 1, wc = wid & 1;
  const int g = lane >> 4, lr = lane & 15;
  const int m0 = blockIdx.y * 128, n0 = blockIdx.x * 128;
  const int srow = tid >> 2, skc = (tid & 3) * 8;

  f32x4 acc[4][4];
#pragma unroll
  for (int i = 0; i < 4; ++i)
#pragma unroll
    for (int j = 0; j < 4; ++j) acc[i][j] = (f32x4){0.f, 0.f, 0.f, 0.f};

  for (int k0 = 0; k0 < HIDDEN; k0 += 32) {
    bf16x8 ah0 = *(const bf16x8*)&Ah[(size_t)(m0 + srow) * HIDDEN + k0 + skc];
    bf16x8 ah1 = *(const bf16x8*)&Ah[(size_t)(m0 + srow + 64) * HIDDEN + k0 + skc];
    bf16x8 al0 = *(const bf16x8*)&Al[(size_t)(m0 + srow) * HIDDEN + k0 + skc];
    bf16x8 al1 = *(const bf16x8*)&Al[(size_t)(m0 + srow + 64) * HIDDEN + k0 + skc];
    bf16x8 wh0 = *(const bf16x8*)&Wh[(size_t)(n0 + srow) * HIDDEN + k0 + skc];
    bf16x8 wh1 = *(const bf16x8*)&Wh[(size_t)(n0 + srow + 64) * HIDDEN + k0 + skc];
    bf16x8 wl0 = *(const bf16x8*)&Wl[(size_t)(n0 + srow) * HIDDEN + k0 + skc];
    bf16x8 wl1 = *(const bf16x8*)&Wl[(size_t)(n0 + srow + 64) * HIDDEN + k0 + skc];
    __syncthreads();
    *(bf16x8*)&Ahs[srow][skc] = ah0; *(bf16x8*)&Ahs[srow + 64][skc] = ah1;
    *(bf16x8*)&Als[srow][skc] = al0; *(bf16x8*)&Als[srow + 64][skc] = al1;
    *(bf16x8*)&Whs[srow][skc] = wh0; *(bf16x8*)&Whs[srow + 64][skc] = wh1;
    *(bf16x8*)&Wls[srow][skc] = wl0; *(bf16x8*)&Wls[srow + 64][skc] = wl1;
    __syncthreads();

    bf16x8 afh[4], afl[4], wfh[4], wfl[4];
#pragma unroll
    for (int mi = 0; mi < 4; ++mi) {
      afh[mi] = *(const bf16x8*)&Ahs[wr * 64 + mi * 16 + lr][g * 8];
      afl[mi] = *(const bf16x8*)&Als[wr * 64 + mi * 16 + lr][g * 8];
    }
#pragma unroll
    for (int ni = 0; ni < 4; ++ni) {
      wfh[ni] = *(const bf16x8*)&Whs[wc * 64 + ni * 16 + lr][g * 8];
      wfl[ni] = *(const bf16x8*)&Wls[wc * 64 + ni * 16 + lr][g * 8];
    }
#pragma unroll
    for (int mi = 0; mi < 4; ++mi)
#pragma unroll
      for (int ni = 0; ni < 4; ++ni) {
        acc[mi][ni] = mfma16(afh[mi], wfh[ni], acc[mi][ni]);
        acc[mi][ni] = mfma16(afh[mi], wfl[ni], acc[mi][ni]);
        acc[mi][ni] = mfma16(afl[mi], wfh[ni], acc[mi][ni]);
      }
  }

#pragma unroll
  for (int mi = 0; mi < 4; ++mi)
#pragma unroll
    for (int ni = 0; ni < 4; ++ni)
#pragma unroll
      for (int r = 0; r < 4; ++r) {
        const int row = m0 + wr * 64 + mi * 16 + g * 4 + r;
        const int col = n0 + wc * 64 + ni * 16 + lr;
        C[(size_t)row * HIDDEN + col] = acc[mi][ni][r];
      }
}

// ---------------------------------------------------------------------------
// MFMA flash attention. Q,K bf16 [BH][SEQ][DH] (Q pre-scaled), Vt bf16
// [BH][DH][SEQ]. Out fp32 [B,S,H,D]. Block: 256 thr / 4 waves; QBLK=128
// (wave: 2 m-blocks of 16 rows); KV tile = 32 keys.
// Swapped QK^T: S^T = mfma(A=K, B=Q) -> lane holds S^T[key 4g+r(+16c)][q=lr].
// ---------------------------------------------------------------------------
__global__ __launch_bounds__(256) void attn_mfma(const unsigned short* __restrict__ Q,
                                                 const unsigned short* __restrict__ K,
                                                 const unsigned short* __restrict__ Vt,
                                                 float* __restrict__ Ab) {
  const int bh = blockIdx.y;
  const int q0 = blockIdx.x * 128;
  const int tid = threadIdx.x;
  const int w = tid >> 6, lane = tid & 63;
  const int g = lane >> 4, lr = lane & 15;
  const unsigned short* Qh = Q + (size_t)bh * SEQ * DH;
  const unsigned short* Kh = K + (size_t)bh * SEQ * DH;
  const unsigned short* Vh = Vt + (size_t)bh * DH * SEQ;

  __shared__ unsigned short Ks[32][136];
  __shared__ unsigned short Vs[128][40];
  __shared__ unsigned short Pw[4][16][40];

  bf16x8 qf[2][4];
#pragma unroll
  for (int m = 0; m < 2; ++m)
#pragma unroll
    for (int kb = 0; kb < 4; ++kb)
      qf[m][kb] = *(const bf16x8*)&Qh[(size_t)(q0 + w * 32 + m * 16 + lr) * DH +
                                      kb * 32 + g * 8];

  f32x4 acc[2][8];
#pragma unroll
  for (int m = 0; m < 2; ++m)
#pragma unroll
    for (int dn = 0; dn < 8; ++dn) acc[m][dn] = (f32x4){0.f, 0.f, 0.f, 0.f};
  float mrun[2] = {-1e30f, -1e30f};
  float lrun[2] = {0.f, 0.f};

  for (int t = 0; t < SEQ; t += 32) {
    __syncthreads();
#pragma unroll
    for (int it = 0; it < 2; ++it) {
      const int s = tid + it * 256;
      const int krow = s >> 4, kc = (s & 15) * 8;
      *(bf16x8*)&Ks[krow][kc] = *(const bf16x8*)&Kh[(size_t)(t + krow) * DH + kc];
      const int d = s >> 2, vkc = (s & 3) * 8;
      *(bf16x8*)&Vs[d][vkc] = *(const bf16x8*)&Vh[(size_t)d * SEQ + t + vkc];
    }
    __syncthreads();

    bf16x8 ap[2];
#pragma unroll
    for (int m = 0; m < 2; ++m) {
      f32x4 st0 = (f32x4){0.f, 0.f, 0.f, 0.f};
      f32x4 st1 = (f32x4){0.f, 0.f, 0.f, 0.f};
#pragma unroll
      for (int kb = 0; kb < 4; ++kb) {
        bf16x8 kf0 = *(const bf16x8*)&Ks[lr][kb * 32 + g * 8];
        bf16x8 kf1 = *(const bf16x8*)&Ks[16 + lr][kb * 32 + g * 8];
        st0 = mfma16(kf0, qf[m][kb], st0);
        st1 = mfma16(kf1, qf[m][kb], st1);
      }
      // softmax over keys for q = lr
      float mt = fmaxf(fmaxf(fmaxf(st0[0], st0[1]), fmaxf(st0[2], st0[3])),
                       fmaxf(fmaxf(st1[0], st1[1]), fmaxf(st1[2], st1[3])));
      mt = fmaxf(mt, __shfl_xor(mt, 16));
      mt = fmaxf(mt, __shfl_xor(mt, 32));
      const float mnew = fmaxf(mrun[m], mt);
      const float corr = __expf(mrun[m] - mnew);
      float p[8], ls = 0.f;
#pragma unroll
      for (int r = 0; r < 4; ++r) {
        p[r] = __expf(st0[r] - mnew);
        p[4 + r] = __expf(st1[r] - mnew);
        ls += p[r] + p[4 + r];
      }
      ls += __shfl_xor(ls, 16);
      ls += __shfl_xor(ls, 32);
      lrun[m] = lrun[m] * corr + ls;
      mrun[m] = mnew;
      // rescale acc rows (acc row q = 4g+r needs corr held at lane 4g+r)
      float cr0 = __shfl(corr, g * 4 + 0);
      float cr1 = __shfl(corr, g * 4 + 1);
      float cr2 = __shfl(corr, g * 4 + 2);
      float cr3 = __shfl(corr, g * 4 + 3);
      const f32x4 cv = (f32x4){cr0, cr1, cr2, cr3};
#pragma unroll
      for (int dn = 0; dn < 8; ++dn) acc[m][dn] *= cv;
      // write P[q][key] as bf16 (keys c*16+4g+r)
      uint2 w0, w1;
      w0.x = pack2bf(p[0], p[1]); w0.y = pack2bf(p[2], p[3]);
      w1.x = pack2bf(p[4], p[5]); w1.y = pack2bf(p[6], p[7]);
      *(uint2*)&Pw[w][lr][4 * g] = w0;
      *(uint2*)&Pw[w][lr][16 + 4 * g] = w1;
      ap[m] = *(const bf16x8*)&Pw[w][lr][8 * g];
    }
    // PV
#pragma unroll
    for (int dn = 0; dn < 8; ++dn) {
      bf16x8 vf = *(const bf16x8*)&Vs[dn * 16 + lr][g * 8];
      acc[0][dn] = mfma16(ap[0], vf, acc[0][dn]);
      acc[1][dn] = mfma16(ap[1], vf, acc[1][dn]);
    }
  }

  const int b = bh >> 4, h = bh & 15;
#pragma unroll
  for (int m = 0; m < 2; ++m) {
    const float inv = 1.f / lrun[m];
    float ir[4];
#pragma unroll
    for (int r = 0; r < 4; ++r) ir[r] = __shfl(inv, g * 4 + r);
#pragma unroll
    for (int dn = 0; dn < 8; ++dn)
#pragma unroll
      for (int r = 0; r < 4; ++r) {
        const int srow = q0 + w * 32 + m * 16 + g * 4 + r;
        Ab[(((size_t)(b * SEQ + srow)) * NHEADS + h) * DH + dn * 16 + lr] =
            acc[m][dn][r] * ir[r];
      }
  }
}

// ---------------------------------------------------------------------------
extern "C" void kernel_launch(void* const* d_in, const int* in_sizes, int n_in,
                              void* d_out, int out_size, void* d_ws,
                              size_t ws_size, hipStream_t stream) {
  const float* X  = (const float*)d_in[0];
  const float* Wq = (const float*)d_in[1];
  const float* Wk = (const float*)d_in[2];
  const float* Wv = (const float*)d_in[3];
  const float* Wo = (const float*)d_in[4];
  float* out = (float*)d_out;

  const int n1 = MTOT * HIDDEN;    // 8388608
  const int n2 = HIDDEN * HIDDEN;  // 4194304

  char* p = (char*)d_ws;
  unsigned short* Qb  = (unsigned short*)(p + 0);          // 16 MB
  unsigned short* Kb  = (unsigned short*)(p + 16777216);   // 16 MB
  unsigned short* Vtg = (unsigned short*)(p + 33554432);   // 16 MB
  unsigned short* Xb  = (unsigned short*)(p + 50331648);   // 16 MB
  unsigned short* Wqb = (unsigned short*)(p + 67108864);   // 8 MB
  unsigned short* Woh = (unsigned short*)(p + 75497472);   // 8 MB
  unsigned short* Wol = (unsigned short*)(p + 83886080);   // 8 MB
  unsigned short* Wkb = (unsigned short*)(p + 92274688);   // 8 MB
  unsigned short* Wvb = (unsigned short*)(p + 100663296);  // 8 MB
  unsigned short* Vb  = (unsigned short*)(p + 109051904);  // 16 MB (ends 125829120)
  float* Abuf = (float*)(p + 92274688);  // 32 MB, aliases Wkb+Wvb+Vb (dead by then)
  unsigned short* Ah = Qb;  // aliases Qb (dead after attention)
  unsigned short* Al = Kb;  // aliases Kb (dead after attention)

  cast_bf16_kernel<<<n1 / 1024, 256, 0, stream>>>(X, Xb, n1);
  cast_bf16_kernel<<<n2 / 1024, 256, 0, stream>>>(Wq, Wqb, n2);
  cast_bf16_kernel<<<n2 / 1024, 256, 0, stream>>>(Wk, Wkb, n2);
  cast_bf16_kernel<<<n2 / 1024, 256, 0, stream>>>(Wv, Wvb, n2);
  cast_split_kernel<<<n2 / 1024, 256, 0, stream>>>(Wo, Woh, Wol, n2);

  const dim3 ggrid(HIDDEN / 128, MTOT / 128);  // (16, 32)
  gemm_bf16<1><<<ggrid, 256, 0, stream>>>(Xb, Wqb, Qb, ATTN_SCALE);
  gemm_bf16<1><<<ggrid, 256, 0, stream>>>(Xb, Wkb, Kb, 1.0f);
  gemm_bf16<1><<<ggrid, 256, 0, stream>>>(Xb, Wvb, Vb, 1.0f);

  transpose_v<<<dim3(SEQ / 32, DH / 32, BH), 256, 0, stream>>>(Vb, Vtg);

  attn_mfma<<<dim3(SEQ / 128, BH), 256, 0, stream>>>(Qb, Kb, Vtg, Abuf);

  cast_split_kernel<<<n1 / 1024, 256, 0, stream>>>(Abuf, Ah, Al, n1);

  gemm_split3<<<ggrid, 256, 0, stream>>>(Ah, Al, Woh, Wol, out);
}

// Round 3
// 339.197 us; speedup vs baseline: 10.4183x; 1.4973x over previous
//
#include <hip/hip_runtime.h>
#include <cstdint>

#define HIDDEN 2048
#define NHEADS 16
#define DH 128
#define BATCH 2
#define SEQ 2048
#define MTOT 4096
#define BH (BATCH * NHEADS)

typedef __attribute__((ext_vector_type(8))) short bf16x8;
typedef __attribute__((ext_vector_type(4))) float f32x4;

// SCALE * log2(e): scores come out of QK^T already in log2 domain
static constexpr float QSCALE = (float)(0.08838834764831845 * 1.4426950408889634);

__device__ __forceinline__ unsigned short f2bf(float f) {
  union { float f; uint32_t u; } v; v.f = f;
  uint32_t r = v.u + 0x7FFFu + ((v.u >> 16) & 1u);
  return (unsigned short)(r >> 16);
}
__device__ __forceinline__ float bf2f(unsigned short h) {
  union { uint32_t u; float f; } v; v.u = ((uint32_t)h) << 16;
  return v.f;
}
__device__ __forceinline__ uint32_t cvtpk(float lo, float hi) {
  uint32_t r;
  asm("v_cvt_pk_bf16_f32 %0, %1, %2" : "=v"(r) : "v"(lo), "v"(hi));
  return r;
}
__device__ __forceinline__ f32x4 mfma16(bf16x8 a, bf16x8 b, f32x4 c) {
  return __builtin_amdgcn_mfma_f32_16x16x32_bf16(a, b, c, 0, 0, 0);
}

typedef const __attribute__((address_space(1))) unsigned char* gas1_t;
typedef __attribute__((address_space(3))) unsigned char* las3_t;
// global -> LDS direct copy, 16B per lane; lds ptr must be wave-uniform base
__device__ __forceinline__ void gll16(const void* g, void* l) {
  __builtin_amdgcn_global_load_lds((gas1_t)g, (las3_t)l, 16, 0, 0);
}

// ---------------------------------------------------------------------------
// casts
// ---------------------------------------------------------------------------
__global__ __launch_bounds__(256) void cast_bf16_kernel(const float* __restrict__ in,
                                                        unsigned short* __restrict__ out,
                                                        int n) {
  int i = (blockIdx.x * 256 + threadIdx.x) * 4;
  if (i < n) {
    float4 f = *(const float4*)&in[i];
    ushort4 o;
    o.x = f2bf(f.x); o.y = f2bf(f.y); o.z = f2bf(f.z); o.w = f2bf(f.w);
    *(ushort4*)&out[i] = o;
  }
}

__global__ __launch_bounds__(256) void cast_split_kernel(const float* __restrict__ in,
                                                         unsigned short* __restrict__ hi,
                                                         unsigned short* __restrict__ lo,
                                                         int n) {
  int i = (blockIdx.x * 256 + threadIdx.x) * 4;
  if (i < n) {
    float4 f = *(const float4*)&in[i];
    ushort4 h, l;
    h.x = f2bf(f.x); l.x = f2bf(f.x - bf2f(h.x));
    h.y = f2bf(f.y); l.y = f2bf(f.y - bf2f(h.y));
    h.z = f2bf(f.z); l.z = f2bf(f.z - bf2f(h.z));
    h.w = f2bf(f.w); l.w = f2bf(f.w - bf2f(h.w));
    *(ushort4*)&hi[i] = h;
    *(ushort4*)&lo[i] = l;
  }
}

// ---------------------------------------------------------------------------
// bf16 GEMM, m97 structure: global_load_lds staging, swizzled source so LDS
// writes are linear and ds_read_b128 fragments are conflict-free.
// C = alpha * A[M,K] @ W[N,K]^T, bf16 out.
// LDS layout per tile: byte(row, kb) = row*64 + (kb ^ ((row>>1)&3))*16
// MODE 0: Q layout [BH][S][D] row-major
// MODE 1: K blocked  [BH][S/32][d/8][s%32][8]   (16B chunks, tile-linear)
// MODE 2: V blocked  [BH][S/8][D][8]            (V^T in 8-key chunks)
// ---------------------------------------------------------------------------
template <int MODE>
__global__ __launch_bounds__(256) void gemm_qkv(const unsigned short* __restrict__ A,
                                                const unsigned short* __restrict__ W,
                                                unsigned short* __restrict__ C,
                                                float alpha) {
  __shared__ __align__(16) unsigned short As[4096];
  __shared__ __align__(16) unsigned short Ws[4096];
  const int tid = threadIdx.x;
  const int lane = tid & 63, wv = tid >> 6;
  const int wr = wv >> 1, wc = wv & 1;
  const int g = lane >> 4, lr = lane & 15;
  const int m0 = blockIdx.y * 128, n0 = blockIdx.x * 128;

  f32x4 acc[4][4];
#pragma unroll
  for (int i = 0; i < 4; ++i)
#pragma unroll
    for (int j = 0; j < 4; ++j) acc[i][j] = (f32x4){0.f, 0.f, 0.f, 0.f};

  // staging chunk assignments (chunk c -> LDS byte c*16)
  const int c0 = tid, c1 = 256 + tid;
  const int row0 = c0 >> 2, kb0 = (c0 & 3) ^ ((row0 >> 1) & 3);
  const int row1 = c1 >> 2, kb1 = (c1 & 3) ^ ((row1 >> 1) & 3);
  const size_t aoff0 = (size_t)(m0 + row0) * HIDDEN + kb0 * 8;
  const size_t aoff1 = (size_t)(m0 + row1) * HIDDEN + kb1 * 8;
  const size_t woff0 = (size_t)(n0 + row0) * HIDDEN + kb0 * 8;
  const size_t woff1 = (size_t)(n0 + row1) * HIDDEN + kb1 * 8;
  const int swz = ((lr >> 1) & 3) * 16;

  for (int k0 = 0; k0 < HIDDEN; k0 += 32) {
    __syncthreads();
    gll16(A + aoff0 + k0, (char*)As + wv * 1024);
    gll16(W + woff0 + k0, (char*)Ws + wv * 1024);
    gll16(A + aoff1 + k0, (char*)As + 4096 + wv * 1024);
    gll16(W + woff1 + k0, (char*)Ws + 4096 + wv * 1024);
    __syncthreads();  // implicit vmcnt(0) drain completes the LDS fills

    bf16x8 af[4], wf[4];
#pragma unroll
    for (int mi = 0; mi < 4; ++mi) {
      const int row = wr * 64 + mi * 16 + lr;
      af[mi] = *(const bf16x8*)((const char*)As + row * 64 + ((g * 16) ^ swz));
    }
#pragma unroll
    for (int ni = 0; ni < 4; ++ni) {
      const int row = wc * 64 + ni * 16 + lr;
      wf[ni] = *(const bf16x8*)((const char*)Ws + row * 64 + ((g * 16) ^ swz));
    }
#pragma unroll
    for (int mi = 0; mi < 4; ++mi)
#pragma unroll
      for (int ni = 0; ni < 4; ++ni)
        acc[mi][ni] = mfma16(af[mi], wf[ni], acc[mi][ni]);
  }

#pragma unroll
  for (int mi = 0; mi < 4; ++mi)
#pragma unroll
    for (int ni = 0; ni < 4; ++ni)
#pragma unroll
      for (int r = 0; r < 4; ++r) {
        const int row = m0 + wr * 64 + mi * 16 + g * 4 + r;
        const int col = n0 + wc * 64 + ni * 16 + lr;
        const unsigned short v = f2bf(acc[mi][ni][r] * alpha);
        const int b = row >> 11, s = row & (SEQ - 1);
        const int h = col >> 7, d = col & (DH - 1);
        const size_t base = (size_t)(b * NHEADS + h) * SEQ * DH;
        if (MODE == 0)
          C[base + (size_t)s * DH + d] = v;
        else if (MODE == 1)
          C[base + (size_t)(s >> 5) * 4096 + (d >> 3) * 256 + (s & 31) * 8 + (d & 7)] = v;
        else
          C[base + (size_t)(s >> 3) * 1024 + d * 8 + (s & 7)] = v;
      }
}

// ---------------------------------------------------------------------------
// Split-bf16x2 O-proj: C(f32) = A_bf16[M,K] @ (Wh+Wl)[N,K]^T
// ---------------------------------------------------------------------------
__global__ __launch_bounds__(256) void gemm_osplit(const unsigned short* __restrict__ A,
                                                   const unsigned short* __restrict__ Wh,
                                                   const unsigned short* __restrict__ Wl,
                                                   float* __restrict__ C) {
  __shared__ __align__(16) unsigned short As[4096];
  __shared__ __align__(16) unsigned short Whs[4096];
  __shared__ __align__(16) unsigned short Wls[4096];
  const int tid = threadIdx.x;
  const int lane = tid & 63, wv = tid >> 6;
  const int wr = wv >> 1, wc = wv & 1;
  const int g = lane >> 4, lr = lane & 15;
  const int m0 = blockIdx.y * 128, n0 = blockIdx.x * 128;

  f32x4 acc[4][4];
#pragma unroll
  for (int i = 0; i < 4; ++i)
#pragma unroll
    for (int j = 0; j < 4; ++j) acc[i][j] = (f32x4){0.f, 0.f, 0.f, 0.f};

  const int c0 = tid, c1 = 256 + tid;
  const int row0 = c0 >> 2, kb0 = (c0 & 3) ^ ((row0 >> 1) & 3);
  const int row1 = c1 >> 2, kb1 = (c1 & 3) ^ ((row1 >> 1) & 3);
  const size_t aoff0 = (size_t)(m0 + row0) * HIDDEN + kb0 * 8;
  const size_t aoff1 = (size_t)(m0 + row1) * HIDDEN + kb1 * 8;
  const size_t woff0 = (size_t)(n0 + row0) * HIDDEN + kb0 * 8;
  const size_t woff1 = (size_t)(n0 + row1) * HIDDEN + kb1 * 8;
  const int swz = ((lr >> 1) & 3) * 16;

  for (int k0 = 0; k0 < HIDDEN; k0 += 32) {
    __syncthreads();
    gll16(A + aoff0 + k0, (char*)As + wv * 1024);
    gll16(Wh + woff0 + k0, (char*)Whs + wv * 1024);
    gll16(Wl + woff0 + k0, (char*)Wls + wv * 1024);
    gll16(A + aoff1 + k0, (char*)As + 4096 + wv * 1024);
    gll16(Wh + woff1 + k0, (char*)Whs + 4096 + wv * 1024);
    gll16(Wl + woff1 + k0, (char*)Wls + 4096 + wv * 1024);
    __syncthreads();

    bf16x8 af[4], wfh[4], wfl[4];
#pragma unroll
    for (int mi = 0; mi < 4; ++mi) {
      const int row = wr * 64 + mi * 16 + lr;
      af[mi] = *(const bf16x8*)((const char*)As + row * 64 + ((g * 16) ^ swz));
    }
#pragma unroll
    for (int ni = 0; ni < 4; ++ni) {
      const int row = wc * 64 + ni * 16 + lr;
      wfh[ni] = *(const bf16x8*)((const char*)Whs + row * 64 + ((g * 16) ^ swz));
      wfl[ni] = *(const bf16x8*)((const char*)Wls + row * 64 + ((g * 16) ^ swz));
    }
#pragma unroll
    for (int mi = 0; mi < 4; ++mi)
#pragma unroll
      for (int ni = 0; ni < 4; ++ni) {
        acc[mi][ni] = mfma16(af[mi], wfh[ni], acc[mi][ni]);
        acc[mi][ni] = mfma16(af[mi], wfl[ni], acc[mi][ni]);
      }
  }

#pragma unroll
  for (int mi = 0; mi < 4; ++mi)
#pragma unroll
    for (int ni = 0; ni < 4; ++ni)
#pragma unroll
      for (int r = 0; r < 4; ++r) {
        const int row = m0 + wr * 64 + mi * 16 + g * 4 + r;
        const int col = n0 + wc * 64 + ni * 16 + lr;
        C[(size_t)row * HIDDEN + col] = acc[mi][ni][r];
      }
}

// ---------------------------------------------------------------------------
// MFMA flash attention, log2-domain scores (Q pre-scaled by SCALE*log2e).
// 256 thr / 4 waves; wave owns 32 q-rows (2 m-blocks of 16); KV tile = 32.
// K blocked [S/32][d/8][s%32][8], V blocked [S/8][D][8] -> tile staging is a
// contiguous 8KB global_load_lds into double-buffered LDS; one barrier/tile,
// next-tile loads in flight across compute. All ds_read_b128 conflict-free.
// Defer-max (THR=8 log2): rescale only when tile max grows materially.
// Output bf16 [B,S,H,D].
// ---------------------------------------------------------------------------
__global__ __launch_bounds__(256, 3) void attn_mfma(const unsigned short* __restrict__ Q,
                                                    const unsigned short* __restrict__ K,
                                                    const unsigned short* __restrict__ V,
                                                    unsigned short* __restrict__ Ab) {
  const int bh = blockIdx.y;
  const int q0 = blockIdx.x * 128;
  const int tid = threadIdx.x;
  const int wv = tid >> 6, lane = tid & 63;
  const int g = lane >> 4, lr = lane & 15;
  const unsigned short* Qh = Q + (size_t)bh * SEQ * DH;
  const unsigned short* Kh = K + (size_t)bh * SEQ * DH;
  const unsigned short* Vh = V + (size_t)bh * SEQ * DH;

  __shared__ __align__(16) unsigned short Kls[2][4096];
  __shared__ __align__(16) unsigned short Vls[2][4096];
  __shared__ __align__(16) unsigned short Pw[4][16][40];

  // Q fragments in registers (row-major global)
  bf16x8 qf[2][4];
#pragma unroll
  for (int m = 0; m < 2; ++m)
#pragma unroll
    for (int kb = 0; kb < 4; ++kb)
      qf[m][kb] = *(const bf16x8*)&Qh[(size_t)(q0 + wv * 32 + m * 16 + lr) * DH +
                                      kb * 32 + g * 8];

  f32x4 acc[2][8];
#pragma unroll
  for (int m = 0; m < 2; ++m)
#pragma unroll
    for (int dn = 0; dn < 8; ++dn) acc[m][dn] = (f32x4){0.f, 0.f, 0.f, 0.f};
  float mrun[2] = {-1e30f, -1e30f};
  float lrun[2] = {0.f, 0.f};

  // prologue: stage tile 0 into buffer 0
#pragma unroll
  for (int j = 0; j < 2; ++j) {
    const int c = j * 256 + tid;
    gll16(Kh + (size_t)c * 8, (char*)&Kls[0][0] + j * 4096 + wv * 1024);
    gll16(Vh + (size_t)c * 8, (char*)&Vls[0][0] + j * 4096 + wv * 1024);
  }

  for (int t = 0; t < SEQ; t += 32) {
    const int cur = (t >> 5) & 1;
    asm volatile("s_waitcnt vmcnt(0)" ::: "memory");
    __syncthreads();
    if (t + 32 < SEQ) {  // issue next tile; flies during this tile's compute
      const unsigned short* Kn = Kh + (size_t)((t + 32) >> 5) * 4096;
      const unsigned short* Vn = Vh + (size_t)((t + 32) >> 3) * 1024;
      char* kb_ = (char*)&Kls[cur ^ 1][0];
      char* vb_ = (char*)&Vls[cur ^ 1][0];
#pragma unroll
      for (int j = 0; j < 2; ++j) {
        const int c = j * 256 + tid;
        gll16(Kn + (size_t)c * 8, kb_ + j * 4096 + wv * 1024);
        gll16(Vn + (size_t)c * 8, vb_ + j * 4096 + wv * 1024);
      }
    }

    const char* Kc = (const char*)&Kls[cur][0];
    const char* Vc = (const char*)&Vls[cur][0];
    bf16x8 ap[2];
#pragma unroll
    for (int m = 0; m < 2; ++m) {
      f32x4 st0 = (f32x4){0.f, 0.f, 0.f, 0.f};
      f32x4 st1 = (f32x4){0.f, 0.f, 0.f, 0.f};
#pragma unroll
      for (int kb = 0; kb < 4; ++kb) {
        const int cb = (kb * 4 + g) * 32;
        bf16x8 kf0 = *(const bf16x8*)(Kc + (cb + lr) * 16);
        bf16x8 kf1 = *(const bf16x8*)(Kc + (cb + 16 + lr) * 16);
        st0 = mfma16(kf0, qf[m][kb], st0);
        st1 = mfma16(kf1, qf[m][kb], st1);
      }
      // tile max for q = lr (keys spread over 8 locals x lanes lr+16c)
      float mt = fmaxf(fmaxf(fmaxf(st0[0], st0[1]), fmaxf(st0[2], st0[3])),
                       fmaxf(fmaxf(st1[0], st1[1]), fmaxf(st1[2], st1[3])));
      mt = fmaxf(mt, __shfl_xor(mt, 16));
      mt = fmaxf(mt, __shfl_xor(mt, 32));
      if (!__all(mt <= mrun[m] + 8.0f)) {  // rare rescale (defer-max)
        const float mnew = fmaxf(mrun[m], mt);
        const float corr = __builtin_amdgcn_exp2f(mrun[m] - mnew);
        lrun[m] *= corr;
        mrun[m] = mnew;
        const f32x4 cv = (f32x4){__shfl(corr, g * 4 + 0), __shfl(corr, g * 4 + 1),
                                 __shfl(corr, g * 4 + 2), __shfl(corr, g * 4 + 3)};
#pragma unroll
        for (int dn = 0; dn < 8; ++dn) acc[m][dn] *= cv;
      }
      float p[8], ls = 0.f;
#pragma unroll
      for (int r = 0; r < 4; ++r) {
        p[r] = __builtin_amdgcn_exp2f(st0[r] - mrun[m]);
        p[4 + r] = __builtin_amdgcn_exp2f(st1[r] - mrun[m]);
        ls += p[r] + p[4 + r];
      }
      ls += __shfl_xor(ls, 16);
      ls += __shfl_xor(ls, 32);
      lrun[m] += ls;
      // pack P (q=lr, keys 16c+4g+r) and repack via LDS into PV A-fragment
      uint2 pk0, pk1;
      pk0.x = cvtpk(p[0], p[1]); pk0.y = cvtpk(p[2], p[3]);
      pk1.x = cvtpk(p[4], p[5]); pk1.y = cvtpk(p[6], p[7]);
      *(uint2*)&Pw[wv][lr][4 * g] = pk0;
      *(uint2*)&Pw[wv][lr][16 + 4 * g] = pk1;
      ap[m] = *(const bf16x8*)&Pw[wv][lr][8 * g];
    }
    // PV: vf = V^T[d = dn*16+lr][keys g*8..+8]
#pragma unroll
    for (int dn = 0; dn < 8; ++dn) {
      bf16x8 vf = *(const bf16x8*)(Vc + (g * 128 + dn * 16 + lr) * 16);
      acc[0][dn] = mfma16(ap[0], vf, acc[0][dn]);
      acc[1][dn] = mfma16(ap[1], vf, acc[1][dn]);
    }
  }

  const int b = bh >> 4, h = bh & 15;
#pragma unroll
  for (int m = 0; m < 2; ++m) {
    const float inv = 1.f / lrun[m];
    float ir[4];
#pragma unroll
    for (int r = 0; r < 4; ++r) ir[r] = __shfl(inv, g * 4 + r);
#pragma unroll
    for (int dn = 0; dn < 8; ++dn)
#pragma unroll
      for (int r = 0; r < 4; ++r) {
        const int srow = q0 + wv * 32 + m * 16 + g * 4 + r;
        Ab[((size_t)(b * SEQ + srow) * NHEADS + h) * DH + dn * 16 + lr] =
            f2bf(acc[m][dn][r] * ir[r]);
      }
  }
}

// ---------------------------------------------------------------------------
extern "C" void kernel_launch(void* const* d_in, const int* in_sizes, int n_in,
                              void* d_out, int out_size, void* d_ws,
                              size_t ws_size, hipStream_t stream) {
  const float* X  = (const float*)d_in[0];
  const float* Wq = (const float*)d_in[1];
  const float* Wk = (const float*)d_in[2];
  const float* Wv = (const float*)d_in[3];
  const float* Wo = (const float*)d_in[4];
  float* out = (float*)d_out;

  const int n1 = MTOT * HIDDEN;    // 8388608
  const int n2 = HIDDEN * HIDDEN;  // 4194304

  char* p = (char*)d_ws;
  unsigned short* Xb  = (unsigned short*)(p + 0);          // 16 MB
  unsigned short* Wqb = (unsigned short*)(p + 16777216);   // 8 MB
  unsigned short* Wkb = (unsigned short*)(p + 25165824);   // 8 MB
  unsigned short* Wvb = (unsigned short*)(p + 33554432);   // 8 MB
  unsigned short* Woh = (unsigned short*)(p + 41943040);   // 8 MB
  unsigned short* Wol = (unsigned short*)(p + 50331648);   // 8 MB
  unsigned short* Qb  = (unsigned short*)(p + 58720256);   // 16 MB
  unsigned short* Kb  = (unsigned short*)(p + 75497472);   // 16 MB
  unsigned short* Vb  = (unsigned short*)(p + 92274688);   // 16 MB
  unsigned short* Ab  = (unsigned short*)(p + 109051904);  // 16 MB (ends 125829120)

  cast_bf16_kernel<<<n1 / 1024, 256, 0, stream>>>(X, Xb, n1);
  cast_bf16_kernel<<<n2 / 1024, 256, 0, stream>>>(Wq, Wqb, n2);
  cast_bf16_kernel<<<n2 / 1024, 256, 0, stream>>>(Wk, Wkb, n2);
  cast_bf16_kernel<<<n2 / 1024, 256, 0, stream>>>(Wv, Wvb, n2);
  cast_split_kernel<<<n2 / 1024, 256, 0, stream>>>(Wo, Woh, Wol, n2);

  const dim3 ggrid(HIDDEN / 128, MTOT / 128);  // (16, 32)
  gemm_qkv<0><<<ggrid, 256, 0, stream>>>(Xb, Wqb, Qb, QSCALE);
  gemm_qkv<1><<<ggrid, 256, 0, stream>>>(Xb, Wkb, Kb, 1.0f);
  gemm_qkv<2><<<ggrid, 256, 0, stream>>>(Xb, Wvb, Vb, 1.0f);

  attn_mfma<<<dim3(SEQ / 128, BH), 256, 0, stream>>>(Qb, Kb, Vb, Ab);

  gemm_osplit<<<ggrid, 256, 0, stream>>>(Ab, Woh, Wol, out);
}